// Round 14
// baseline (568.318 us; speedup 1.0000x reference)
//
#include <hip/hip_runtime.h>
#include <hip/hip_bf16.h>

typedef __hip_bfloat16 bf16;

constexpr int NN = 50000;           // nodes
constexpr int NE = 800000;          // edges (without self loops)
constexpr int NT = NE + NN;         // edges incl self loops
constexpr int NNB  = (NN + 127)/128; // 391 fill buckets (128 dsts each)
constexpr int NPART = 8;             // XCD partitions (blockIdx & 7)
constexpr int PCAP = 512;            // slots per (bucket, partition); mean 256, 16 sigma

// flag-selected load: f32 storage vs bf16 storage
__device__ __forceinline__ float cvt(const void* p, long long i, int f32){
  return f32 ? ((const float*)p)[i] : __bfloat162float(((const bf16*)p)[i]);
}
// bf16 <-> f32 (RNE pack)
__device__ __forceinline__ unsigned short f2bf(float f){
  unsigned u = __float_as_uint(f);
  u += 0x7fffu + ((u >> 16) & 1);
  return (unsigned short)(u >> 16);
}
__device__ __forceinline__ float bflo(unsigned p){ return __uint_as_float(p << 16); }
__device__ __forceinline__ float bfhi(unsigned p){ return __uint_as_float(p & 0xffff0000u); }
__device__ __forceinline__ float bf2f(unsigned short u){ return __uint_as_float((unsigned)u << 16); }
// monotone float<->uint key for atomicMax
__device__ __forceinline__ unsigned f2key(float f){
  unsigned u = __float_as_uint(f);
  return (u & 0x80000000u) ? ~u : (u | 0x80000000u);
}
__device__ __forceinline__ float key2f(unsigned k){
  unsigned u = (k & 0x80000000u) ? (k & 0x7fffffffu) : ~k;
  return __uint_as_float(u);
}

// Storage-dtype detector (see R2 notes): flag=1 => f32 storage, 0 => bf16.
__global__ void k_detect(const void* w, int n, int* flag){
  __shared__ int bad;
  if(threadIdx.x == 0) bad = 0;
  __syncthreads();
  const unsigned short* p = (const unsigned short*)w;
  int local = 0;
  for(int i = threadIdx.x; i < n; i += 256){
    int e = (p[i] >> 7) & 0xFF;
    if(e >= 0xC0) local = 1;
  }
  if(local) atomicOr(&bad, 1);
  __syncthreads();
  if(threadIdx.x == 0) *flag = bad;
}

struct SrcPtrs { const void* p[12]; };
__global__ void k_cvtall(SrcPtrs sp, float* Wc, const int* flag){
  const int sz[12]  = {8192,64,4096,64,8192,128,128,128,8192,64,64,32};
  const int off[12] = {0,8192,8256,12352,12416,20608,20736,20864,20992,29184,29248,29312};
  int b = blockIdx.x;
  int f = *flag;
  const void* src = sp.p[b];
  float* dst = Wc + off[b];
  int n = sz[b];
  for(int i = threadIdx.x; i < n; i += 256) dst[i] = cvt(src, i, f);
}

// ---------------- CSR build: XCD-partitioned bin -> bucket-local scatter ----------------
__global__ void k_bin(const int* __restrict__ ei, int* __restrict__ bcur,
                      unsigned* __restrict__ tmp){
  int e = blockIdx.x*256 + threadIdx.x;
  int p = blockIdx.x & (NPART-1);
  if(e < NE){
    int dst = ei[NE + e];
    int src = ei[e];
    int b = dst >> 7;
    int pos = atomicAdd(&bcur[(p*NNB + b)*16], 1);
    if(pos < PCAP) tmp[((size_t)(b*NPART + p) << 9) + pos] = (unsigned)src | ((unsigned)(dst & 127) << 16);
  }
}
__global__ void k_btot(const int* __restrict__ bcur, int* __restrict__ bbase){
  __shared__ int sh[2][512];
  int t = threadIdx.x;
  int tot = 0;
  if(t < NNB){
    for(int p = 0; p < NPART; p++) tot += bcur[(p*NNB + t)*16];
    tot += min(128, NN - (t << 7));       // self loops
  }
  sh[0][t] = tot;
  __syncthreads();
  int cur = 0;
  for(int off = 1; off < 512; off <<= 1){
    int nxt = cur^1;
    int v = sh[cur][t];
    if(t >= off) v += sh[cur][t-off];
    sh[nxt][t] = v;
    __syncthreads();
    cur = nxt;
  }
  if(t < NNB) bbase[t] = sh[cur][t] - tot;  // exclusive
}
__global__ void k_scatter(const int* __restrict__ bcur, const int* __restrict__ bbase,
                          const unsigned* __restrict__ tmp, int* __restrict__ rowptr,
                          int* __restrict__ rowend, float* __restrict__ dinv,
                          unsigned short* __restrict__ srcidx16){
  __shared__ int hist[128];
  __shared__ int lcur[128];
  __shared__ int sh[2][128];
  int b = blockIdx.x;
  int dst0 = b << 7;
  int nd = min(128, NN - dst0);
  int tid = threadIdx.x;
  if(tid < 128) hist[tid] = 0;
  __syncthreads();
  for(int p = 0; p < NPART; p++){
    int cnt = min(bcur[(p*NNB + b)*16], PCAP);
    const unsigned* tp = tmp + ((size_t)(b*NPART + p) << 9);
    for(int i = tid; i < cnt; i += 256) atomicAdd(&hist[tp[i] >> 16], 1);
  }
  __syncthreads();
  int c = (tid < 128) ? hist[tid] + 1 : 0;     // +1 self loop
  if(tid < 128) sh[0][tid] = c;
  __syncthreads();
  int cur = 0;
  for(int off = 1; off < 128; off <<= 1){
    int nxt = cur^1;
    if(tid < 128){
      int v = sh[cur][tid];
      if(tid >= off) v += sh[cur][tid-off];
      sh[nxt][tid] = v;
    }
    __syncthreads();
    cur = nxt;
  }
  if(tid < nd){
    int rp = bbase[b] + sh[cur][tid] - c;
    int d = dst0 + tid;
    rowptr[d] = rp;
    srcidx16[rp] = (unsigned short)d;          // self-loop at row start
    rowend[d] = rp + c;
    dinv[d] = rsqrtf((float)c);
    lcur[tid] = rp + 1;
  }
  __syncthreads();
  for(int p = 0; p < NPART; p++){
    int cnt = min(bcur[(p*NNB + b)*16], PCAP);
    const unsigned* tp = tmp + ((size_t)(b*NPART + p) << 9);
    for(int i = tid; i < cnt; i += 256){
      unsigned v = tp[i];
      int pos = atomicAdd(&lcur[v >> 16], 1);
      srcidx16[pos] = (unsigned short)(v & 0xffffu);
    }
  }
}

// ---------------- dense layers ----------------
// Unified GEMM. BF16IN: X rows are bf16. PACKED: head-interleaved uint2 output
// AND fused attention scores (s,d per head + global Smax) — GAT layers only.
template<int KIN, int KOUT, bool SCALE, bool PACKED, bool BF16IN>
__global__ void k_gemm(const void* __restrict__ Xv, const float* __restrict__ W,
                       const float* __restrict__ dinv, void* __restrict__ out,
                       const float* __restrict__ asrc,   // adst = asrc + KOUT
                       float* __restrict__ sS, float* __restrict__ sD,
                       unsigned* __restrict__ SmaxKey){
  constexpr int TPR = KOUT/4;          // threads per row
  constexpr int R = 256/TPR;           // rows per block
  constexpr int HALF = KOUT/2;
  __shared__ float Wl[KIN*KOUT];
  __shared__ float Xl[R][KIN+4];
  __shared__ unsigned sk0, sk1;
  int tid = threadIdx.x;
  if(PACKED && tid == 0){ sk0 = 0; sk1 = 0; }
  for(int i = tid; i < KIN*KOUT/4; i += 256)
    ((float4*)Wl)[i] = ((const float4*)W)[i];
  int row0 = blockIdx.x*R;
  for(int i = tid; i < R*KIN/4; i += 256){
    int r = i/(KIN/4), k4 = i - r*(KIN/4);
    int rr = row0 + r;
    float4 v;
    if(rr < NN){
      if(BF16IN){
        ushort4 u = ((const ushort4*)Xv)[(size_t)rr*(KIN/4) + k4];
        v.x = bf2f(u.x); v.y = bf2f(u.y); v.z = bf2f(u.z); v.w = bf2f(u.w);
      } else {
        v = ((const float4*)Xv)[(size_t)rr*(KIN/4) + k4];
      }
    } else v = make_float4(0.f,0.f,0.f,0.f);
    *(float4*)&Xl[r][k4*4] = v;
  }
  __syncthreads();
  int ty = tid/TPR, tx = tid - ty*TPR;
  int row = row0 + ty;
  float a0=0.f, a1=0.f, a2=0.f, a3=0.f;
  if(row < NN){
    if(PACKED){
#pragma unroll
      for(int k = 0; k < KIN; k++){
        float xv = Xl[ty][k];
        float2 wa = *(const float2*)&Wl[k*KOUT + 2*tx];
        float2 wb = *(const float2*)&Wl[k*KOUT + HALF + 2*tx];
        a0 += xv*wa.x; a1 += xv*wa.y; a2 += xv*wb.x; a3 += xv*wb.y;
      }
    } else {
#pragma unroll
      for(int k = 0; k < KIN; k++){
        float xv = Xl[ty][k];
        float4 w = *(const float4*)&Wl[k*KOUT + tx*4];
        a0 += xv*w.x; a1 += xv*w.y; a2 += xv*w.z; a3 += xv*w.w;
      }
    }
  }
  if(PACKED){
    // fused per-(row,head) attention scores; adst = asrc + KOUT
    const float* adst = asrc + KOUT;
    float s0 = a0*asrc[2*tx] + a1*asrc[2*tx+1];
    float s1 = a2*asrc[HALF + 2*tx] + a3*asrc[HALF + 2*tx+1];
    float d0 = a0*adst[2*tx] + a1*adst[2*tx+1];
    float d1 = a2*adst[HALF + 2*tx] + a3*adst[HALF + 2*tx+1];
#pragma unroll
    for(int off = TPR/2; off; off >>= 1){
      s0 += __shfl_xor(s0, off, TPR); s1 += __shfl_xor(s1, off, TPR);
      d0 += __shfl_xor(d0, off, TPR); d1 += __shfl_xor(d1, off, TPR);
    }
    if(tx == 0 && row < NN){
      float2 sv; sv.x = s0; sv.y = s1;
      float2 dv; dv.x = d0; dv.y = d1;
      *(float2*)(sS + 2*row) = sv;
      *(float2*)(sD + 2*row) = dv;
      atomicMax(&sk0, f2key(s0));
      atomicMax(&sk1, f2key(s1));
    }
    // packed store
    if(row < NN){
      uint2 o;
      o.x = (unsigned)f2bf(a0) | ((unsigned)f2bf(a2) << 16);
      o.y = (unsigned)f2bf(a1) | ((unsigned)f2bf(a3) << 16);
      *(uint2*)((unsigned*)out + (size_t)row*HALF + 2*tx) = o;
    }
    __syncthreads();
    if(tid == 0){
      atomicMax(&SmaxKey[0], sk0);
      atomicMax(&SmaxKey[1], sk1);
    }
  } else {
    if(row < NN){
      float s = SCALE ? dinv[row] : 1.0f;
      ushort4 o;
      o.x = f2bf(a0*s); o.y = f2bf(a1*s); o.z = f2bf(a2*s); o.w = f2bf(a3*s);
      *(ushort4*)((unsigned short*)out + (size_t)row*KOUT + tx*4) = o;
    }
  }
}

// layer-1 GEMM: X via dtype flag, bf16 out, dinv prescale
template<int KIN, int KOUT, bool SCALE>
__global__ void k_gemm_in(const void* __restrict__ X, const float* __restrict__ W,
                          const float* __restrict__ dinv, unsigned short* __restrict__ Au,
                          const int* __restrict__ flag){
  constexpr int TPR = KOUT/4;
  constexpr int R = 256/TPR;
  __shared__ float Wl[KIN*KOUT];
  __shared__ float Xl[R][KIN+4];
  int tid = threadIdx.x;
  int f = *flag;
  for(int i = tid; i < KIN*KOUT/4; i += 256)
    ((float4*)Wl)[i] = ((const float4*)W)[i];
  int row0 = blockIdx.x*R;
  for(int i = tid; i < R*KIN; i += 256){
    int r = i/KIN, k = i - r*KIN;
    int rr = row0 + r;
    Xl[r][k] = (rr < NN) ? cvt(X, (long long)rr*KIN + k, f) : 0.0f;
  }
  __syncthreads();
  int ty = tid/TPR, tx = tid - ty*TPR;
  int row = row0 + ty;
  if(row >= NN) return;
  float a0=0.f, a1=0.f, a2=0.f, a3=0.f;
#pragma unroll
  for(int k = 0; k < KIN; k++){
    float xv = Xl[ty][k];
    float4 w = *(const float4*)&Wl[k*KOUT + tx*4];
    a0 += xv*w.x; a1 += xv*w.y; a2 += xv*w.z; a3 += xv*w.w;
  }
  float s = SCALE ? dinv[row] : 1.0f;
  ushort4 o;
  o.x = f2bf(a0*s); o.y = f2bf(a1*s); o.z = f2bf(a2*s); o.w = f2bf(a3*s);
  *(ushort4*)(Au + (size_t)row*KOUT + tx*4) = o;
}

// ---------------- gather aggregations (one wave per dst node) ----------------
// GCN: 8 lanes/edge, 8 edges/iter; row = 64 bf16 = 8 uint4 slots; bf16 output.
__global__ void k_gcn_gather(const int* __restrict__ rowptr, const int* __restrict__ rowend,
                             const unsigned short* __restrict__ srcidx16, const float* __restrict__ dinv,
                             const unsigned* __restrict__ Au32, const float* __restrict__ bias,
                             unsigned short* __restrict__ Bu){
  int wid = threadIdx.x >> 6, lane = threadIdx.x & 63;
  int n = blockIdx.x*4 + wid;
  if(n >= NN) return;
  int s0 = rowptr[n], ne = rowend[n] - s0;
  int o = lane >> 3, c4 = lane & 7;
  float a0=0,a1=0,a2=0,a3=0,a4=0,a5=0,a6=0,a7=0;
  for(int base = 0; base < ne; base += 64){
    int my = base + lane;
    int src = (my < ne) ? (int)srcidx16[s0 + my] : -1;
    int cnt = min(64, ne - base);
    int iters = (cnt + 7) >> 3;
#pragma unroll 4
    for(int j = 0; j < iters; j++){
      int sb = __shfl(src, 8*j + o);
      if(sb >= 0){
        uint4 p = *(const uint4*)(Au32 + (size_t)sb*32 + c4*4);
        a0 += bflo(p.x); a1 += bfhi(p.x);
        a2 += bflo(p.y); a3 += bfhi(p.y);
        a4 += bflo(p.z); a5 += bfhi(p.z);
        a6 += bflo(p.w); a7 += bfhi(p.w);
      }
    }
  }
#pragma unroll
  for(int off = 8; off <= 32; off <<= 1){
    a0 += __shfl_xor(a0, off); a1 += __shfl_xor(a1, off);
    a2 += __shfl_xor(a2, off); a3 += __shfl_xor(a3, off);
    a4 += __shfl_xor(a4, off); a5 += __shfl_xor(a5, off);
    a6 += __shfl_xor(a6, off); a7 += __shfl_xor(a7, off);
  }
  if(o == 0){
    float dn = dinv[n];
    int cb = 8*c4;
    uint4 st;
    st.x = (unsigned)f2bf(fmaxf(a0*dn + bias[cb+0], 0.0f)) | ((unsigned)f2bf(fmaxf(a1*dn + bias[cb+1], 0.0f)) << 16);
    st.y = (unsigned)f2bf(fmaxf(a2*dn + bias[cb+2], 0.0f)) | ((unsigned)f2bf(fmaxf(a3*dn + bias[cb+3], 0.0f)) << 16);
    st.z = (unsigned)f2bf(fmaxf(a4*dn + bias[cb+4], 0.0f)) | ((unsigned)f2bf(fmaxf(a5*dn + bias[cb+5], 0.0f)) << 16);
    st.w = (unsigned)f2bf(fmaxf(a6*dn + bias[cb+6], 0.0f)) | ((unsigned)f2bf(fmaxf(a7*dn + bias[cb+7], 0.0f)) << 16);
    *(uint4*)(Bu + (size_t)n*64 + cb) = st;
  }
}

// GAT1 (heads=2, C=64, concat): single-pass softmax via global-bound m̂;
// 16 lanes/edge, 4 edges/iter; bf16 output rows of 128.
__global__ void k_gat1_gather(const int* __restrict__ rowptr, const int* __restrict__ rowend,
                              const unsigned short* __restrict__ srcidx16, const float* __restrict__ sS,
                              const float* __restrict__ sD, const unsigned* __restrict__ Ab,
                              const float* __restrict__ bias, unsigned short* __restrict__ Bu,
                              const unsigned* __restrict__ SmaxKey){
  int wid = threadIdx.x >> 6, lane = threadIdx.x & 63;
  int n = blockIdx.x*4 + wid;
  if(n >= NN) return;
  int s0 = rowptr[n], ne = rowend[n] - s0;
  float d0 = sD[n*2], d1 = sD[n*2+1];
  float t0 = key2f(SmaxKey[0]) + d0;  float m0 = t0 > 0.0f ? t0 : 0.2f*t0;
  float t1 = key2f(SmaxKey[1]) + d1;  float m1 = t1 > 0.0f ? t1 : 0.2f*t1;
  int q = lane >> 4, c4 = lane & 15;
  float z0 = 0.0f, z1 = 0.0f;
  float b0=0,b1=0,b2=0,b3=0, c0=0,c1=0,c2=0,c3=0;
  for(int base = 0; base < ne; base += 64){
    int my = base + lane;
    int src = 0; float w0 = 0.0f, w1 = 0.0f;
    if(my < ne){
      src = (int)srcidx16[s0 + my];
      float2 sv = *(const float2*)(sS + src*2);
      float e0 = sv.x + d0; e0 = e0 > 0.0f ? e0 : 0.2f*e0;
      float e1 = sv.y + d1; e1 = e1 > 0.0f ? e1 : 0.2f*e1;
      w0 = __expf(e0 - m0); w1 = __expf(e1 - m1);
      z0 += w0; z1 += w1;
    }
    int cnt = min(64, ne - base);
    int iters = (cnt + 3) >> 2;
#pragma unroll 4
    for(int j = 0; j < iters; j++){
      int idx = 4*j + q;
      int sb = __shfl(src, idx);
      float a0 = __shfl(w0, idx), a1 = __shfl(w1, idx);
      uint4 p = *(const uint4*)(Ab + (size_t)sb*64 + c4*4);
      b0 += bflo(p.x)*a0; c0 += bfhi(p.x)*a1;
      b1 += bflo(p.y)*a0; c1 += bfhi(p.y)*a1;
      b2 += bflo(p.z)*a0; c2 += bfhi(p.z)*a1;
      b3 += bflo(p.w)*a0; c3 += bfhi(p.w)*a1;
    }
  }
#pragma unroll
  for(int off = 1; off <= 32; off <<= 1){ z0 += __shfl_xor(z0, off); z1 += __shfl_xor(z1, off); }
#pragma unroll
  for(int off = 16; off <= 32; off <<= 1){
    b0 += __shfl_xor(b0, off); b1 += __shfl_xor(b1, off);
    b2 += __shfl_xor(b2, off); b3 += __shfl_xor(b3, off);
    c0 += __shfl_xor(c0, off); c1 += __shfl_xor(c1, off);
    c2 += __shfl_xor(c2, off); c3 += __shfl_xor(c3, off);
  }
  if(q == 0){
    float iz0 = 1.0f/(z0 + 1e-16f), iz1 = 1.0f/(z1 + 1e-16f);
    int cb = 4*c4;
    uint2 s0v, s1v;
    s0v.x = (unsigned)f2bf(fmaxf(b0*iz0 + bias[cb+0], 0.0f)) | ((unsigned)f2bf(fmaxf(b1*iz0 + bias[cb+1], 0.0f)) << 16);
    s0v.y = (unsigned)f2bf(fmaxf(b2*iz0 + bias[cb+2], 0.0f)) | ((unsigned)f2bf(fmaxf(b3*iz0 + bias[cb+3], 0.0f)) << 16);
    s1v.x = (unsigned)f2bf(fmaxf(c0*iz1 + bias[64+cb+0], 0.0f)) | ((unsigned)f2bf(fmaxf(c1*iz1 + bias[64+cb+1], 0.0f)) << 16);
    s1v.y = (unsigned)f2bf(fmaxf(c2*iz1 + bias[64+cb+2], 0.0f)) | ((unsigned)f2bf(fmaxf(c3*iz1 + bias[64+cb+3], 0.0f)) << 16);
    *(uint2*)(Bu + (size_t)n*128 + cb)      = s0v;
    *(uint2*)(Bu + (size_t)n*128 + 64 + cb) = s1v;
  }
}

// GAT2 (heads=2, C=32, mean) + bias + log_softmax, single-pass softmax;
// 8 lanes/edge, 8 edges/iter.
__global__ void k_gat2_final(const int* __restrict__ rowptr, const int* __restrict__ rowend,
                             const unsigned short* __restrict__ srcidx16, const float* __restrict__ sS,
                             const float* __restrict__ sD, const unsigned* __restrict__ Ab,
                             const float* __restrict__ bias, void* __restrict__ out,
                             const int* __restrict__ flag, const unsigned* __restrict__ SmaxKey){
  int wid = threadIdx.x >> 6, lane = threadIdx.x & 63;
  int n = blockIdx.x*4 + wid;
  if(n >= NN) return;
  int s0 = rowptr[n], ne = rowend[n] - s0;
  float d0 = sD[n*2], d1 = sD[n*2+1];
  float t0 = key2f(SmaxKey[0]) + d0;  float m0 = t0 > 0.0f ? t0 : 0.2f*t0;
  float t1 = key2f(SmaxKey[1]) + d1;  float m1 = t1 > 0.0f ? t1 : 0.2f*t1;
  int o = lane >> 3, c4 = lane & 7;
  float z0 = 0.0f, z1 = 0.0f;
  float b0=0,b1=0,b2=0,b3=0, c0=0,c1=0,c2=0,c3=0;
  for(int base = 0; base < ne; base += 64){
    int my = base + lane;
    int src = 0; float w0 = 0.0f, w1 = 0.0f;
    if(my < ne){
      src = (int)srcidx16[s0 + my];
      float2 sv = *(const float2*)(sS + src*2);
      float e0 = sv.x + d0; e0 = e0 > 0.0f ? e0 : 0.2f*e0;
      float e1 = sv.y + d1; e1 = e1 > 0.0f ? e1 : 0.2f*e1;
      w0 = __expf(e0 - m0); w1 = __expf(e1 - m1);
      z0 += w0; z1 += w1;
    }
    int cnt = min(64, ne - base);
    int iters = (cnt + 7) >> 3;
#pragma unroll 4
    for(int j = 0; j < iters; j++){
      int idx = 8*j + o;
      int sb = __shfl(src, idx);
      float a0 = __shfl(w0, idx), a1 = __shfl(w1, idx);
      uint4 p = *(const uint4*)(Ab + (size_t)sb*32 + c4*4);
      b0 += bflo(p.x)*a0; c0 += bfhi(p.x)*a1;
      b1 += bflo(p.y)*a0; c1 += bfhi(p.y)*a1;
      b2 += bflo(p.z)*a0; c2 += bfhi(p.z)*a1;
      b3 += bflo(p.w)*a0; c3 += bfhi(p.w)*a1;
    }
  }
#pragma unroll
  for(int off = 1; off <= 32; off <<= 1){ z0 += __shfl_xor(z0, off); z1 += __shfl_xor(z1, off); }
#pragma unroll
  for(int off = 8; off <= 32; off <<= 1){
    b0 += __shfl_xor(b0, off); b1 += __shfl_xor(b1, off);
    b2 += __shfl_xor(b2, off); b3 += __shfl_xor(b3, off);
    c0 += __shfl_xor(c0, off); c1 += __shfl_xor(c1, off);
    c2 += __shfl_xor(c2, off); c3 += __shfl_xor(c3, off);
  }
  float iz0 = 1.0f/(z0 + 1e-16f), iz1 = 1.0f/(z1 + 1e-16f);
  int cb = 4*c4;
  float o0 = 0.5f*(b0*iz0 + c0*iz1) + bias[cb+0];
  float o1 = 0.5f*(b1*iz0 + c1*iz1) + bias[cb+1];
  float o2 = 0.5f*(b2*iz0 + c2*iz1) + bias[cb+2];
  float o3 = 0.5f*(b3*iz0 + c3*iz1) + bias[cb+3];
  float mx = fmaxf(fmaxf(o0, o1), fmaxf(o2, o3));
  for(int off = 4; off; off >>= 1) mx = fmaxf(mx, __shfl_xor(mx, off));
  float sm = __expf(o0 - mx) + __expf(o1 - mx) + __expf(o2 - mx) + __expf(o3 - mx);
  for(int off = 4; off; off >>= 1) sm += __shfl_xor(sm, off);
  float lse = mx + __logf(sm);
  if(o == 0){
    if(*flag){
      float4 r;
      r.x = o0 - lse; r.y = o1 - lse; r.z = o2 - lse; r.w = o3 - lse;
      *(float4*)((float*)out + (size_t)n*32 + cb) = r;
    } else {
      uint2 r;
      r.x = (unsigned)f2bf(o0 - lse) | ((unsigned)f2bf(o1 - lse) << 16);
      r.y = (unsigned)f2bf(o2 - lse) | ((unsigned)f2bf(o3 - lse) << 16);
      *(uint2*)((unsigned*)out + (size_t)n*16 + 2*c4) = r;
    }
  }
}

extern "C" void kernel_launch(void* const* d_in, const int* in_sizes, int n_in,
                              void* d_out, int out_size, void* d_ws, size_t ws_size,
                              hipStream_t stream) {
  const void* x   = d_in[0];
  const int*  ei  = (const int*)d_in[1];

  // workspace layout:
  // A-region: Au bf16 [NN*64] (GCN feats) | Ab u32 [NN*64] at +12.8MB (GAT packed feats)
  // Bu bf16 [NN*128] | dinv | sS | sD | rowptr | rowend |
  // srcidx16[NT] | bcur[8*391*16 padded] | bbase[391] | tmp[391*8*512] u32 | Wc | flag | SmaxKey[2]
  float* A    = (float*)d_ws;
  unsigned short* Au = (unsigned short*)A;
  unsigned* Au32 = (unsigned*)A;
  unsigned* Ab = (unsigned*)(A + (size_t)NN*64);   // +12.8MB
  unsigned short* Bu = (unsigned short*)(A + (size_t)NN*128);
  float* dinv = A + (size_t)NN*128 + (size_t)NN*64;  // after Bu (NN*128 ushort = NN*64 floats)
  float* sS   = dinv + NN;
  float* sD   = sS + 2*NN;
  int* rowptr = (int*)(sD + 2*NN);
  int* rowend = rowptr + NN;
  unsigned short* srcidx16 = (unsigned short*)(rowend + NN);
  int* bcur   = (int*)(srcidx16 + NT + 2);
  int* bbase  = bcur + NPART*NNB*16;
  unsigned* tmp = (unsigned*)(bbase + NNB + 1);
  float* Wc   = (float*)(tmp + (size_t)NNB*NPART*PCAP);
  int*  flag  = (int*)(Wc + 29344);
  unsigned* SmaxKey = (unsigned*)(flag + 1);

  const float* W1c  = Wc;
  const float* b1c  = Wc + 8192;
  const float* W2c  = Wc + 8256;
  const float* b2c  = Wc + 12352;
  const float* Wg1c = Wc + 12416;
  const float* as1c = Wc + 20608;   // adst follows at +128 (contiguous)
  const float* bg1c = Wc + 20864;
  const float* Wg2c = Wc + 20992;
  const float* as2c = Wc + 29184;   // adst follows at +64 (contiguous)
  const float* bg2c = Wc + 29312;

  auto nb = [](long long t){ return dim3((unsigned)((t + 255)/256)); };
  dim3 gnodes((NN + 3)/4);      // 4 waves/block, 1 wave per node

  // dtype detect + weight conversion
  k_detect<<<1, 256, 0, stream>>>(d_in[2], 8192, flag);
  SrcPtrs sp;
  for(int i = 0; i < 12; i++) sp.p[i] = d_in[2 + i];
  k_cvtall<<<12, 256, 0, stream>>>(sp, Wc, flag);

  // CSR build — XCD-partitioned bin (64B-padded cursors), totals scan, bucket-local scatter
  hipMemsetAsync(bcur, 0, NPART*NNB*16*4, stream);
  k_bin<<<nb(NE), 256, 0, stream>>>(ei, bcur, tmp);
  k_btot<<<1, 512, 0, stream>>>(bcur, bbase);
  k_scatter<<<NNB, 256, 0, stream>>>(bcur, bbase, tmp, rowptr, rowend, dinv, srcidx16);

  // ---- GCN1 ----  (GEMM prescales rows by dinv, writes bf16)
  k_gemm_in<128,64,true><<<dim3((NN+15)/16), 256, 0, stream>>>(x, W1c, dinv, Au, flag);
  k_gcn_gather<<<gnodes, 256, 0, stream>>>(rowptr, rowend, srcidx16, dinv, Au32, b1c, Bu);

  // ---- GCN2 ----  (bf16 input, bf16 output)
  k_gemm<64,64,true,false,true><<<dim3((NN+15)/16), 256, 0, stream>>>(Bu, W2c, dinv, Au, nullptr, nullptr, nullptr, nullptr);
  k_gcn_gather<<<gnodes, 256, 0, stream>>>(rowptr, rowend, srcidx16, dinv, Au32, b2c, Bu);

  // ---- GAT1: heads=2, C=64, concat ----  (GEMM: packed output + fused scores)
  hipMemsetAsync(SmaxKey, 0, 8, stream);
  k_gemm<64,128,false,true,true><<<dim3((NN+7)/8), 256, 0, stream>>>(Bu, Wg1c, dinv, Ab, as1c, sS, sD, SmaxKey);
  k_gat1_gather<<<gnodes, 256, 0, stream>>>(rowptr, rowend, srcidx16, sS, sD, Ab, bg1c, Bu, SmaxKey);

  // ---- GAT2: heads=2, C=32, mean + log_softmax ----
  hipMemsetAsync(SmaxKey, 0, 8, stream);
  k_gemm<128,64,false,true,true><<<dim3((NN+15)/16), 256, 0, stream>>>(Bu, Wg2c, dinv, Ab, as2c, sS, sD, SmaxKey);
  k_gat2_final<<<gnodes, 256, 0, stream>>>(rowptr, rowend, srcidx16, sS, sD, Ab, bg2c, d_out, flag, SmaxKey);
}

// Round 15
// 417.573 us; speedup vs baseline: 1.3610x; 1.3610x over previous
//
#include <hip/hip_runtime.h>
#include <hip/hip_bf16.h>

typedef __hip_bfloat16 bf16;

constexpr int NN = 50000;           // nodes
constexpr int NE = 800000;          // edges (without self loops)
constexpr int NT = NE + NN;         // edges incl self loops
constexpr int NNB  = (NN + 127)/128; // 391 fill buckets (128 dsts each)
constexpr int NPART = 8;             // XCD partitions (blockIdx & 7)
constexpr int PCAP = 512;            // slots per (bucket, partition); mean 256, 16 sigma

// flag-selected load: f32 storage vs bf16 storage
__device__ __forceinline__ float cvt(const void* p, long long i, int f32){
  return f32 ? ((const float*)p)[i] : __bfloat162float(((const bf16*)p)[i]);
}
// bf16 <-> f32 (RNE pack)
__device__ __forceinline__ unsigned short f2bf(float f){
  unsigned u = __float_as_uint(f);
  u += 0x7fffu + ((u >> 16) & 1);
  return (unsigned short)(u >> 16);
}
__device__ __forceinline__ float bflo(unsigned p){ return __uint_as_float(p << 16); }
__device__ __forceinline__ float bfhi(unsigned p){ return __uint_as_float(p & 0xffff0000u); }
// monotone float<->uint key for atomicMax
__device__ __forceinline__ unsigned f2key(float f){
  unsigned u = __float_as_uint(f);
  return (u & 0x80000000u) ? ~u : (u | 0x80000000u);
}
__device__ __forceinline__ float key2f(unsigned k){
  unsigned u = (k & 0x80000000u) ? (k & 0x7fffffffu) : ~k;
  return __uint_as_float(u);
}

// Storage-dtype detector (see R2 notes): flag=1 => f32 storage, 0 => bf16.
__global__ void k_detect(const void* w, int n, int* flag){
  __shared__ int bad;
  if(threadIdx.x == 0) bad = 0;
  __syncthreads();
  const unsigned short* p = (const unsigned short*)w;
  int local = 0;
  for(int i = threadIdx.x; i < n; i += 256){
    int e = (p[i] >> 7) & 0xFF;
    if(e >= 0xC0) local = 1;
  }
  if(local) atomicOr(&bad, 1);
  __syncthreads();
  if(threadIdx.x == 0) *flag = bad;
}

struct SrcPtrs { const void* p[12]; };
__global__ void k_cvtall(SrcPtrs sp, float* Wc, const int* flag){
  const int sz[12]  = {8192,64,4096,64,8192,128,128,128,8192,64,64,32};
  const int off[12] = {0,8192,8256,12352,12416,20608,20736,20864,20992,29184,29248,29312};
  int b = blockIdx.x;
  int f = *flag;
  const void* src = sp.p[b];
  float* dst = Wc + off[b];
  int n = sz[b];
  for(int i = threadIdx.x; i < n; i += 256) dst[i] = cvt(src, i, f);
}

// ---------------- CSR build: XCD-partitioned bin -> bucket-local scatter ----------------
// phase 1: bin edges into (bucket, partition=blockIdx&7) fixed-capacity slots.
// cursors 64B-padded (one line each): per-line atomic serialization ~256 atomics/line.
__global__ void k_bin(const int* __restrict__ ei, int* __restrict__ bcur,
                      unsigned* __restrict__ tmp){
  int e = blockIdx.x*256 + threadIdx.x;
  int p = blockIdx.x & (NPART-1);
  if(e < NE){
    int dst = ei[NE + e];
    int src = ei[e];
    int b = dst >> 7;
    int pos = atomicAdd(&bcur[(p*NNB + b)*16], 1);
    if(pos < PCAP) tmp[((size_t)(b*NPART + p) << 9) + pos] = (unsigned)src | ((unsigned)(dst & 127) << 16);
  }
}
// bucket totals (edges + self-loops) -> exclusive scan -> bbase
__global__ void k_btot(const int* __restrict__ bcur, int* __restrict__ bbase){
  __shared__ int sh[2][512];
  int t = threadIdx.x;
  int tot = 0;
  if(t < NNB){
    for(int p = 0; p < NPART; p++) tot += bcur[(p*NNB + t)*16];
    tot += min(128, NN - (t << 7));       // self loops
  }
  sh[0][t] = tot;
  __syncthreads();
  int cur = 0;
  for(int off = 1; off < 512; off <<= 1){
    int nxt = cur^1;
    int v = sh[cur][t];
    if(t >= off) v += sh[cur][t-off];
    sh[nxt][t] = v;
    __syncthreads();
    cur = nxt;
  }
  if(t < NNB) bbase[t] = sh[cur][t] - tot;  // exclusive
}
// per-bucket: LDS histogram -> local scan -> rowptr/dinv/self-loop/rowend -> scatter
__global__ void k_scatter(const int* __restrict__ bcur, const int* __restrict__ bbase,
                          const unsigned* __restrict__ tmp, int* __restrict__ rowptr,
                          int* __restrict__ rowend, float* __restrict__ dinv,
                          unsigned short* __restrict__ srcidx16){
  __shared__ int hist[128];
  __shared__ int lcur[128];
  __shared__ int sh[2][128];
  int b = blockIdx.x;
  int dst0 = b << 7;
  int nd = min(128, NN - dst0);
  int tid = threadIdx.x;
  if(tid < 128) hist[tid] = 0;
  __syncthreads();
  // histogram over the bucket's 8 partition streams
  for(int p = 0; p < NPART; p++){
    int cnt = min(bcur[(p*NNB + b)*16], PCAP);
    const unsigned* tp = tmp + ((size_t)(b*NPART + p) << 9);
    for(int i = tid; i < cnt; i += 256) atomicAdd(&hist[tp[i] >> 16], 1);
  }
  __syncthreads();
  // exclusive scan of (hist[t]+1) over 128 dsts (first 128 threads)
  int c = (tid < 128) ? hist[tid] + 1 : 0;     // +1 self loop
  if(tid < 128) sh[0][tid] = c;
  __syncthreads();
  int cur = 0;
  for(int off = 1; off < 128; off <<= 1){
    int nxt = cur^1;
    if(tid < 128){
      int v = sh[cur][tid];
      if(tid >= off) v += sh[cur][tid-off];
      sh[nxt][tid] = v;
    }
    __syncthreads();
    cur = nxt;
  }
  if(tid < nd){
    int rp = bbase[b] + sh[cur][tid] - c;
    int d = dst0 + tid;
    rowptr[d] = rp;
    srcidx16[rp] = (unsigned short)d;          // self-loop at row start
    rowend[d] = rp + c;                        // c = hist+1
    dinv[d] = rsqrtf((float)c);
    lcur[tid] = rp + 1;
  }
  __syncthreads();
  // scatter
  for(int p = 0; p < NPART; p++){
    int cnt = min(bcur[(p*NNB + b)*16], PCAP);
    const unsigned* tp = tmp + ((size_t)(b*NPART + p) << 9);
    for(int i = tid; i < cnt; i += 256){
      unsigned v = tp[i];
      int pos = atomicAdd(&lcur[v >> 16], 1);
      srcidx16[pos] = (unsigned short)(v & 0xffffu);
    }
  }
}

// ---------------- dense layers ----------------
// PACKED=false: plain bf16 rows (ushort4 store). PACKED=true: head-interleaved
// (h0[c]|h1[c]<<16) rows of KOUT/2 dwords (uint2 store) — feeds GAT gathers directly.
template<int KIN, int KOUT, bool SCALE, bool PACKED>
__global__ void k_gemm_f(const float* __restrict__ X, const float* __restrict__ W,
                         const float* __restrict__ dinv, void* __restrict__ out){
  constexpr int TPR = KOUT/4;          // threads per row
  constexpr int R = 256/TPR;           // rows per block
  constexpr int HALF = KOUT/2;
  __shared__ float Wl[KIN*KOUT];
  __shared__ float Xl[R][KIN+4];
  int tid = threadIdx.x;
  for(int i = tid; i < KIN*KOUT/4; i += 256)
    ((float4*)Wl)[i] = ((const float4*)W)[i];
  int row0 = blockIdx.x*R;
  for(int i = tid; i < R*KIN/4; i += 256){
    int r = i/(KIN/4), k4 = i - r*(KIN/4);
    int rr = row0 + r;
    float4 v = (rr < NN) ? ((const float4*)(X + (size_t)rr*KIN))[k4]
                         : make_float4(0.f,0.f,0.f,0.f);
    *(float4*)&Xl[r][k4*4] = v;
  }
  __syncthreads();
  int ty = tid/TPR, tx = tid - ty*TPR;
  int row = row0 + ty;
  if(row >= NN) return;
  float a0=0.f, a1=0.f, a2=0.f, a3=0.f;
  if(PACKED){
#pragma unroll
    for(int k = 0; k < KIN; k++){
      float xv = Xl[ty][k];
      float2 wa = *(const float2*)&Wl[k*KOUT + 2*tx];
      float2 wb = *(const float2*)&Wl[k*KOUT + HALF + 2*tx];
      a0 += xv*wa.x; a1 += xv*wa.y; a2 += xv*wb.x; a3 += xv*wb.y;
    }
  } else {
#pragma unroll
    for(int k = 0; k < KIN; k++){
      float xv = Xl[ty][k];
      float4 w = *(const float4*)&Wl[k*KOUT + tx*4];
      a0 += xv*w.x; a1 += xv*w.y; a2 += xv*w.z; a3 += xv*w.w;
    }
  }
  float s = SCALE ? dinv[row] : 1.0f;
  if(PACKED){
    uint2 o;
    o.x = (unsigned)f2bf(a0*s) | ((unsigned)f2bf(a2*s) << 16);
    o.y = (unsigned)f2bf(a1*s) | ((unsigned)f2bf(a3*s) << 16);
    *(uint2*)((unsigned*)out + (size_t)row*HALF + 2*tx) = o;
  } else {
    ushort4 o;
    o.x = f2bf(a0*s); o.y = f2bf(a1*s); o.z = f2bf(a2*s); o.w = f2bf(a3*s);
    *(ushort4*)((unsigned short*)out + (size_t)row*KOUT + tx*4) = o;
  }
}

template<int KIN, int KOUT, bool SCALE>
__global__ void k_gemm_in(const void* __restrict__ X, const float* __restrict__ W,
                          const float* __restrict__ dinv, unsigned short* __restrict__ Au,
                          const int* __restrict__ flag){
  constexpr int TPR = KOUT/4;
  constexpr int R = 256/TPR;
  __shared__ float Wl[KIN*KOUT];
  __shared__ float Xl[R][KIN+4];
  int tid = threadIdx.x;
  int f = *flag;
  for(int i = tid; i < KIN*KOUT/4; i += 256)
    ((float4*)Wl)[i] = ((const float4*)W)[i];
  int row0 = blockIdx.x*R;
  for(int i = tid; i < R*KIN; i += 256){
    int r = i/KIN, k = i - r*KIN;
    int rr = row0 + r;
    Xl[r][k] = (rr < NN) ? cvt(X, (long long)rr*KIN + k, f) : 0.0f;
  }
  __syncthreads();
  int ty = tid/TPR, tx = tid - ty*TPR;
  int row = row0 + ty;
  if(row >= NN) return;
  float a0=0.f, a1=0.f, a2=0.f, a3=0.f;
#pragma unroll
  for(int k = 0; k < KIN; k++){
    float xv = Xl[ty][k];
    float4 w = *(const float4*)&Wl[k*KOUT + tx*4];
    a0 += xv*w.x; a1 += xv*w.y; a2 += xv*w.z; a3 += xv*w.w;
  }
  float s = SCALE ? dinv[row] : 1.0f;
  ushort4 o;
  o.x = f2bf(a0*s); o.y = f2bf(a1*s); o.z = f2bf(a2*s); o.w = f2bf(a3*s);
  *(ushort4*)(Au + (size_t)row*KOUT + tx*4) = o;
}

// per (node, head) attention scores from PACKED features; block-reduce Smax
template<int C>
__global__ void k_gat_scores(const unsigned* __restrict__ Ab, const float* __restrict__ asrc,
                             const float* __restrict__ adst, float* __restrict__ sS,
                             float* __restrict__ sD, unsigned* __restrict__ SmaxKey){
  __shared__ unsigned shm[256];
  int tid = threadIdx.x;
  int i = blockIdx.x*256 + tid;
  float s = 0.0f, d = 0.0f;
  if(i < NN*2){
    int node = i >> 1, h = i & 1;
    const unsigned* hp = Ab + (size_t)node*C;
#pragma unroll
    for(int c = 0; c < C; c++){
      unsigned p = hp[c];
      float v = h ? bfhi(p) : bflo(p);
      s += v * asrc[h*C + c];
      d += v * adst[h*C + c];
    }
    sS[i] = s; sD[i] = d;
    shm[tid] = f2key(s);
  } else shm[tid] = 0;
  __syncthreads();
  // parity-preserving max reduce: shm[0]=max h0, shm[1]=max h1
  for(int off = 128; off >= 2; off >>= 1){
    if(tid < off) shm[tid] = max(shm[tid], shm[tid + off]);
    __syncthreads();
  }
  if(tid < 2) atomicMax(&SmaxKey[tid], shm[tid]);
}

// ---------------- gather aggregations (one wave per dst node) ----------------
// GCN: 8 lanes/edge, 8 edges/iter; row = 64 bf16 = 8 uint4 slots.
__global__ void k_gcn_gather(const int* __restrict__ rowptr, const int* __restrict__ rowend,
                             const unsigned short* __restrict__ srcidx16, const float* __restrict__ dinv,
                             const unsigned* __restrict__ Au32, const float* __restrict__ bias,
                             float* __restrict__ B){
  int wid = threadIdx.x >> 6, lane = threadIdx.x & 63;
  int n = blockIdx.x*4 + wid;
  if(n >= NN) return;
  int s0 = rowptr[n], ne = rowend[n] - s0;
  int o = lane >> 3, c4 = lane & 7;
  float a0=0,a1=0,a2=0,a3=0,a4=0,a5=0,a6=0,a7=0;
  for(int base = 0; base < ne; base += 64){
    int my = base + lane;
    int src = (my < ne) ? (int)srcidx16[s0 + my] : -1;
    int cnt = min(64, ne - base);
    int iters = (cnt + 7) >> 3;
#pragma unroll 4
    for(int j = 0; j < iters; j++){
      int sb = __shfl(src, 8*j + o);
      if(sb >= 0){
        uint4 p = *(const uint4*)(Au32 + (size_t)sb*32 + c4*4);
        a0 += bflo(p.x); a1 += bfhi(p.x);
        a2 += bflo(p.y); a3 += bfhi(p.y);
        a4 += bflo(p.z); a5 += bfhi(p.z);
        a6 += bflo(p.w); a7 += bfhi(p.w);
      }
    }
  }
#pragma unroll
  for(int off = 8; off <= 32; off <<= 1){
    a0 += __shfl_xor(a0, off); a1 += __shfl_xor(a1, off);
    a2 += __shfl_xor(a2, off); a3 += __shfl_xor(a3, off);
    a4 += __shfl_xor(a4, off); a5 += __shfl_xor(a5, off);
    a6 += __shfl_xor(a6, off); a7 += __shfl_xor(a7, off);
  }
  if(o == 0){
    float dn = dinv[n];
    int cb = 8*c4;
    float4 v0, v1;
    v0.x = fmaxf(a0*dn + bias[cb+0], 0.0f);
    v0.y = fmaxf(a1*dn + bias[cb+1], 0.0f);
    v0.z = fmaxf(a2*dn + bias[cb+2], 0.0f);
    v0.w = fmaxf(a3*dn + bias[cb+3], 0.0f);
    v1.x = fmaxf(a4*dn + bias[cb+4], 0.0f);
    v1.y = fmaxf(a5*dn + bias[cb+5], 0.0f);
    v1.z = fmaxf(a6*dn + bias[cb+6], 0.0f);
    v1.w = fmaxf(a7*dn + bias[cb+7], 0.0f);
    *(float4*)(B + (size_t)n*64 + cb)     = v0;
    *(float4*)(B + (size_t)n*64 + cb + 4) = v1;
  }
}

// GAT1 (heads=2, C=64, concat): single-pass softmax via global-bound m̂;
// 16 lanes/edge, 4 edges/iter.
__global__ void k_gat1_gather(const int* __restrict__ rowptr, const int* __restrict__ rowend,
                              const unsigned short* __restrict__ srcidx16, const float* __restrict__ sS,
                              const float* __restrict__ sD, const unsigned* __restrict__ Ab,
                              const float* __restrict__ bias, float* __restrict__ B,
                              const unsigned* __restrict__ SmaxKey){
  int wid = threadIdx.x >> 6, lane = threadIdx.x & 63;
  int n = blockIdx.x*4 + wid;
  if(n >= NN) return;
  int s0 = rowptr[n], ne = rowend[n] - s0;
  float d0 = sD[n*2], d1 = sD[n*2+1];
  float t0 = key2f(SmaxKey[0]) + d0;  float m0 = t0 > 0.0f ? t0 : 0.2f*t0;
  float t1 = key2f(SmaxKey[1]) + d1;  float m1 = t1 > 0.0f ? t1 : 0.2f*t1;
  int q = lane >> 4, c4 = lane & 15;
  float z0 = 0.0f, z1 = 0.0f;
  float b0=0,b1=0,b2=0,b3=0, c0=0,c1=0,c2=0,c3=0;
  for(int base = 0; base < ne; base += 64){
    int my = base + lane;
    int src = 0; float w0 = 0.0f, w1 = 0.0f;
    if(my < ne){
      src = (int)srcidx16[s0 + my];
      float2 sv = *(const float2*)(sS + src*2);
      float e0 = sv.x + d0; e0 = e0 > 0.0f ? e0 : 0.2f*e0;
      float e1 = sv.y + d1; e1 = e1 > 0.0f ? e1 : 0.2f*e1;
      w0 = __expf(e0 - m0); w1 = __expf(e1 - m1);
      z0 += w0; z1 += w1;
    }
    int cnt = min(64, ne - base);
    int iters = (cnt + 3) >> 2;
#pragma unroll 4
    for(int j = 0; j < iters; j++){
      int idx = 4*j + q;
      int sb = __shfl(src, idx);
      float a0 = __shfl(w0, idx), a1 = __shfl(w1, idx);
      uint4 p = *(const uint4*)(Ab + (size_t)sb*64 + c4*4);
      b0 += bflo(p.x)*a0; c0 += bfhi(p.x)*a1;
      b1 += bflo(p.y)*a0; c1 += bfhi(p.y)*a1;
      b2 += bflo(p.z)*a0; c2 += bfhi(p.z)*a1;
      b3 += bflo(p.w)*a0; c3 += bfhi(p.w)*a1;
    }
  }
#pragma unroll
  for(int off = 1; off <= 32; off <<= 1){ z0 += __shfl_xor(z0, off); z1 += __shfl_xor(z1, off); }
#pragma unroll
  for(int off = 16; off <= 32; off <<= 1){
    b0 += __shfl_xor(b0, off); b1 += __shfl_xor(b1, off);
    b2 += __shfl_xor(b2, off); b3 += __shfl_xor(b3, off);
    c0 += __shfl_xor(c0, off); c1 += __shfl_xor(c1, off);
    c2 += __shfl_xor(c2, off); c3 += __shfl_xor(c3, off);
  }
  if(q == 0){
    float iz0 = 1.0f/(z0 + 1e-16f), iz1 = 1.0f/(z1 + 1e-16f);
    int cb = 4*c4;
    float4 o0, o1;
    o0.x = fmaxf(b0*iz0 + bias[cb+0], 0.0f);
    o0.y = fmaxf(b1*iz0 + bias[cb+1], 0.0f);
    o0.z = fmaxf(b2*iz0 + bias[cb+2], 0.0f);
    o0.w = fmaxf(b3*iz0 + bias[cb+3], 0.0f);
    o1.x = fmaxf(c0*iz1 + bias[64+cb+0], 0.0f);
    o1.y = fmaxf(c1*iz1 + bias[64+cb+1], 0.0f);
    o1.z = fmaxf(c2*iz1 + bias[64+cb+2], 0.0f);
    o1.w = fmaxf(c3*iz1 + bias[64+cb+3], 0.0f);
    *(float4*)(B + (size_t)n*128 + cb)      = o0;
    *(float4*)(B + (size_t)n*128 + 64 + cb) = o1;
  }
}

// GAT2 (heads=2, C=32, mean) + bias + log_softmax, single-pass softmax;
// 8 lanes/edge, 8 edges/iter.
__global__ void k_gat2_final(const int* __restrict__ rowptr, const int* __restrict__ rowend,
                             const unsigned short* __restrict__ srcidx16, const float* __restrict__ sS,
                             const float* __restrict__ sD, const unsigned* __restrict__ Ab,
                             const float* __restrict__ bias, void* __restrict__ out,
                             const int* __restrict__ flag, const unsigned* __restrict__ SmaxKey){
  int wid = threadIdx.x >> 6, lane = threadIdx.x & 63;
  int n = blockIdx.x*4 + wid;
  if(n >= NN) return;
  int s0 = rowptr[n], ne = rowend[n] - s0;
  float d0 = sD[n*2], d1 = sD[n*2+1];
  float t0 = key2f(SmaxKey[0]) + d0;  float m0 = t0 > 0.0f ? t0 : 0.2f*t0;
  float t1 = key2f(SmaxKey[1]) + d1;  float m1 = t1 > 0.0f ? t1 : 0.2f*t1;
  int o = lane >> 3, c4 = lane & 7;
  float z0 = 0.0f, z1 = 0.0f;
  float b0=0,b1=0,b2=0,b3=0, c0=0,c1=0,c2=0,c3=0;
  for(int base = 0; base < ne; base += 64){
    int my = base + lane;
    int src = 0; float w0 = 0.0f, w1 = 0.0f;
    if(my < ne){
      src = (int)srcidx16[s0 + my];
      float2 sv = *(const float2*)(sS + src*2);
      float e0 = sv.x + d0; e0 = e0 > 0.0f ? e0 : 0.2f*e0;
      float e1 = sv.y + d1; e1 = e1 > 0.0f ? e1 : 0.2f*e1;
      w0 = __expf(e0 - m0); w1 = __expf(e1 - m1);
      z0 += w0; z1 += w1;
    }
    int cnt = min(64, ne - base);
    int iters = (cnt + 7) >> 3;
#pragma unroll 4
    for(int j = 0; j < iters; j++){
      int idx = 8*j + o;
      int sb = __shfl(src, idx);
      float a0 = __shfl(w0, idx), a1 = __shfl(w1, idx);
      uint4 p = *(const uint4*)(Ab + (size_t)sb*32 + c4*4);
      b0 += bflo(p.x)*a0; c0 += bfhi(p.x)*a1;
      b1 += bflo(p.y)*a0; c1 += bfhi(p.y)*a1;
      b2 += bflo(p.z)*a0; c2 += bfhi(p.z)*a1;
      b3 += bflo(p.w)*a0; c3 += bfhi(p.w)*a1;
    }
  }
#pragma unroll
  for(int off = 1; off <= 32; off <<= 1){ z0 += __shfl_xor(z0, off); z1 += __shfl_xor(z1, off); }
#pragma unroll
  for(int off = 8; off <= 32; off <<= 1){
    b0 += __shfl_xor(b0, off); b1 += __shfl_xor(b1, off);
    b2 += __shfl_xor(b2, off); b3 += __shfl_xor(b3, off);
    c0 += __shfl_xor(c0, off); c1 += __shfl_xor(c1, off);
    c2 += __shfl_xor(c2, off); c3 += __shfl_xor(c3, off);
  }
  float iz0 = 1.0f/(z0 + 1e-16f), iz1 = 1.0f/(z1 + 1e-16f);
  int cb = 4*c4;
  float o0 = 0.5f*(b0*iz0 + c0*iz1) + bias[cb+0];
  float o1 = 0.5f*(b1*iz0 + c1*iz1) + bias[cb+1];
  float o2 = 0.5f*(b2*iz0 + c2*iz1) + bias[cb+2];
  float o3 = 0.5f*(b3*iz0 + c3*iz1) + bias[cb+3];
  float mx = fmaxf(fmaxf(o0, o1), fmaxf(o2, o3));
  for(int off = 4; off; off >>= 1) mx = fmaxf(mx, __shfl_xor(mx, off));
  float sm = __expf(o0 - mx) + __expf(o1 - mx) + __expf(o2 - mx) + __expf(o3 - mx);
  for(int off = 4; off; off >>= 1) sm += __shfl_xor(sm, off);
  float lse = mx + __logf(sm);
  if(o == 0){
    if(*flag){
      float4 r;
      r.x = o0 - lse; r.y = o1 - lse; r.z = o2 - lse; r.w = o3 - lse;
      *(float4*)((float*)out + (size_t)n*32 + cb) = r;
    } else {
      uint2 r;
      r.x = (unsigned)f2bf(o0 - lse) | ((unsigned)f2bf(o1 - lse) << 16);
      r.y = (unsigned)f2bf(o2 - lse) | ((unsigned)f2bf(o3 - lse) << 16);
      *(uint2*)((unsigned*)out + (size_t)n*16 + 2*c4) = r;
    }
  }
}

extern "C" void kernel_launch(void* const* d_in, const int* in_sizes, int n_in,
                              void* d_out, int out_size, void* d_ws, size_t ws_size,
                              hipStream_t stream) {
  const void* x   = d_in[0];
  const int*  ei  = (const int*)d_in[1];

  // workspace layout:
  // A-region 25.6MB: Au bf16 [NN*64] (GCN) | Ab u32 [NN*64] at +12.8MB (GAT packed)
  // B[NN*128] f32 | dinv | sS | sD | rowptr | rowend |
  // srcidx16[NT] | bcur[8*391*16 padded] | bbase[391] | tmp[391*8*512] u32 | Wc | flag | SmaxKey[2]
  float* A    = (float*)d_ws;
  unsigned short* Au = (unsigned short*)A;
  unsigned* Au32 = (unsigned*)A;
  unsigned* Ab = (unsigned*)(A + (size_t)NN*64);   // +12.8MB
  float* B    = A + (size_t)NN*128;
  float* dinv = B + (size_t)NN*128;
  float* sS   = dinv + NN;
  float* sD   = sS + 2*NN;
  int* rowptr = (int*)(sD + 2*NN);
  int* rowend = rowptr + NN;
  unsigned short* srcidx16 = (unsigned short*)(rowend + NN);
  int* bcur   = (int*)(srcidx16 + NT + 2);
  int* bbase  = bcur + NPART*NNB*16;
  unsigned* tmp = (unsigned*)(bbase + NNB + 1);
  float* Wc   = (float*)(tmp + (size_t)NNB*NPART*PCAP);
  int*  flag  = (int*)(Wc + 29344);
  unsigned* SmaxKey = (unsigned*)(flag + 1);

  const float* W1c  = Wc;
  const float* b1c  = Wc + 8192;
  const float* W2c  = Wc + 8256;
  const float* b2c  = Wc + 12352;
  const float* Wg1c = Wc + 12416;
  const float* as1c = Wc + 20608;
  const float* ad1c = Wc + 20736;
  const float* bg1c = Wc + 20864;
  const float* Wg2c = Wc + 20992;
  const float* as2c = Wc + 29184;
  const float* ad2c = Wc + 29248;
  const float* bg2c = Wc + 29312;

  auto nb = [](long long t){ return dim3((unsigned)((t + 255)/256)); };
  dim3 gnodes((NN + 3)/4);      // 4 waves/block, 1 wave per node

  // dtype detect + weight conversion
  k_detect<<<1, 256, 0, stream>>>(d_in[2], 8192, flag);
  SrcPtrs sp;
  for(int i = 0; i < 12; i++) sp.p[i] = d_in[2 + i];
  k_cvtall<<<12, 256, 0, stream>>>(sp, Wc, flag);

  // CSR build — XCD-partitioned bin (64B-padded cursors), totals scan, bucket-local scatter
  hipMemsetAsync(bcur, 0, NPART*NNB*16*4, stream);
  k_bin<<<nb(NE), 256, 0, stream>>>(ei, bcur, tmp);
  k_btot<<<1, 512, 0, stream>>>(bcur, bbase);
  k_scatter<<<NNB, 256, 0, stream>>>(bcur, bbase, tmp, rowptr, rowend, dinv, srcidx16);

  // ---- GCN1 ----  (GEMM prescales rows by dinv, writes bf16)
  k_gemm_in<128,64,true><<<dim3((NN+15)/16), 256, 0, stream>>>(x, W1c, dinv, Au, flag);
  k_gcn_gather<<<gnodes, 256, 0, stream>>>(rowptr, rowend, srcidx16, dinv, Au32, b1c, B);

  // ---- GCN2 ----
  k_gemm_f<64,64,true,false><<<dim3((NN+15)/16), 256, 0, stream>>>(B, W2c, dinv, Au);
  k_gcn_gather<<<gnodes, 256, 0, stream>>>(rowptr, rowend, srcidx16, dinv, Au32, b2c, B);

  // ---- GAT1: heads=2, C=64, concat ----  (GEMM writes packed head-interleaved)
  k_gemm_f<64,128,false,true><<<dim3((NN+7)/8), 256, 0, stream>>>(B, Wg1c, dinv, Ab);
  hipMemsetAsync(SmaxKey, 0, 8, stream);
  k_gat_scores<64><<<nb((long long)NN*2), 256, 0, stream>>>(Ab, as1c, ad1c, sS, sD, SmaxKey);
  k_gat1_gather<<<gnodes, 256, 0, stream>>>(rowptr, rowend, srcidx16, sS, sD, Ab, bg1c, B, SmaxKey);

  // ---- GAT2: heads=2, C=32, mean + log_softmax ----
  k_gemm_f<128,64,false,true><<<dim3((NN+15)/16), 256, 0, stream>>>(B, Wg2c, dinv, Ab);
  hipMemsetAsync(SmaxKey, 0, 8, stream);
  k_gat_scores<32><<<nb((long long)NN*2), 256, 0, stream>>>(Ab, as2c, ad2c, sS, sD, SmaxKey);
  k_gat2_final<<<gnodes, 256, 0, stream>>>(rowptr, rowend, srcidx16, sS, sD, Ab, bg2c, d_out, flag, SmaxKey);
}